// Round 13
// baseline (180.181 us; speedup 1.0000x reference)
//
#include <hip/hip_runtime.h>
#include <hip/hip_bf16.h>
#include <stdint.h>

// Problem constants: B=4, N=4096, D=1024, H=16, M=256, DH=64
#define DATA_SCALE 0.35355339059327373f  // 64^-0.25
#define DN_SCALE   0.0625f               // 0.5 * 64^-0.5

typedef __bf16 bf16x8 __attribute__((ext_vector_type(8)));
typedef float  f32x4  __attribute__((ext_vector_type(4)));

static __device__ __forceinline__ unsigned short f2bf(float f) {
    union { __bf16 b; unsigned short u; } t;
    t.b = (__bf16)f;
    return t.u;
}

static __device__ __forceinline__ f32x4 mfma16(bf16x8 a, bf16x8 b, f32x4 c) {
    return __builtin_amdgcn_mfma_f32_16x16x32_bf16(a, b, c, 0, 0, 0);
}

static __device__ __forceinline__ void gload16(const void* g, void* lds) {
    __builtin_amdgcn_global_load_lds(
        (const __attribute__((address_space(1))) unsigned int*)g,
        (__attribute__((address_space(3))) unsigned int*)lds, 16, 0, 0);
}

union U8 { unsigned short s[8]; __bf16 b[8]; bf16x8 v; };
union P4 { __bf16 b[4]; uint2 u2; };

// ---------------------------------------------------------------- prep ----
__global__ __launch_bounds__(256) void k_prep(const float* __restrict__ W,
                                              const float* __restrict__ proj,
                                              unsigned short* __restrict__ Wb,
                                              unsigned short* __restrict__ projs,
                                              unsigned short* __restrict__ projs_swz) {
    int i = blockIdx.x * 256 + threadIdx.x;
    if (i < 1024 * 1024) Wb[i] = f2bf(W[i]);
    if (i < 256 * 64) {
        const int row = i >> 6, col = i & 63;
        unsigned short v = f2bf(proj[i] * DATA_SCALE);
        projs[i] = v;
        projs_swz[row * 64 + (col ^ ((row & 7) << 3))] = v;
    }
}

// ------------------------------------------------------------- k_ctx ------
// R13: ALL proj B-fragments hoisted to registers (S-GEMM = 32 pure-register
// MFMAs); pjL LDS buffer + staging deleted (LDS 78.8KB -> 46KB). R12's hoist
// economics (+64 logical -> +28 physical VGPR) predicts ~215-230 VGPR,
// still 2 waves/SIMD. Spill tripwire: WRITE_SIZE must stay 33MB.
__global__ __launch_bounds__(256) void k_ctx(const float* __restrict__ kg,
                                             const float* __restrict__ vg,
                                             const unsigned short* __restrict__ projs,
                                             float* __restrict__ ctx_part,
                                             float* __restrict__ ksum_part,
                                             int cshift, int ntiles) {
    const int bh = blockIdx.x >> cshift, chunk = blockIdx.x & ((1 << cshift) - 1);
    const int b = bh >> 4, h = bh & 15;
    const int tid = threadIdx.x;
    const int w = tid >> 6, lane = tid & 63, l15 = lane & 15, hh = lane >> 4;

    __shared__ __align__(16) unsigned short kpT[256][72];
    __shared__ __align__(16) unsigned short VT[64][72];

    // ---- hoist ALL proj B-fragments (loop-invariant) ----
    bf16x8 pb0r[16], pb1r[16];
#pragma unroll
    for (int ni = 0; ni < 16; ++ni) {
        pb0r[ni] = *(const bf16x8*)(projs + (size_t)(16*ni + l15) * 64 + 8*hh);
        pb1r[ni] = *(const bf16x8*)(projs + (size_t)(16*ni + l15) * 64 + 32 + 8*hh);
    }

    f32x4 cacc[4][4];
#pragma unroll
    for (int i = 0; i < 4; ++i)
#pragma unroll
        for (int j = 0; j < 4; ++j) cacc[i][j] = (f32x4){0.f, 0.f, 0.f, 0.f};
    float ksacc[16];
#pragma unroll
    for (int i = 0; i < 16; ++i) ksacc[i] = 0.f;

    const size_t rowoff = (size_t)(b * 4096 + chunk * ntiles * 64) * 1024 + h * 64;

    const float* vbase = vg + rowoff + (size_t)lane * 1024 + w * 16;
    const float* kbase = kg + rowoff + (size_t)(16*w + l15) * 1024 + hh * 8;

    float4 v0 = *(const float4*)(vbase);
    float4 v1 = *(const float4*)(vbase + 4);
    float4 v2 = *(const float4*)(vbase + 8);
    float4 v3 = *(const float4*)(vbase + 12);
    float4 k0 = *(const float4*)(kbase);
    float4 k1 = *(const float4*)(kbase + 4);
    float4 k2 = *(const float4*)(kbase + 32);
    float4 k3 = *(const float4*)(kbase + 36);

    for (int tt = 0; tt < ntiles; ++tt) {
        __syncthreads();   // A: prev tile's kpT/VT reads done

        {
            const int n = lane, cs = w * 16;
            VT[cs+ 0][n] = f2bf(v0.x); VT[cs+ 1][n] = f2bf(v0.y);
            VT[cs+ 2][n] = f2bf(v0.z); VT[cs+ 3][n] = f2bf(v0.w);
            VT[cs+ 4][n] = f2bf(v1.x); VT[cs+ 5][n] = f2bf(v1.y);
            VT[cs+ 6][n] = f2bf(v1.z); VT[cs+ 7][n] = f2bf(v1.w);
            VT[cs+ 8][n] = f2bf(v2.x); VT[cs+ 9][n] = f2bf(v2.y);
            VT[cs+10][n] = f2bf(v2.z); VT[cs+11][n] = f2bf(v2.w);
            VT[cs+12][n] = f2bf(v3.x); VT[cs+13][n] = f2bf(v3.y);
            VT[cs+14][n] = f2bf(v3.z); VT[cs+15][n] = f2bf(v3.w);
        }

        float s2 = k0.x*k0.x + k0.y*k0.y + k0.z*k0.z + k0.w*k0.w
                 + k1.x*k1.x + k1.y*k1.y + k1.z*k1.z + k1.w*k1.w
                 + k2.x*k2.x + k2.y*k2.y + k2.z*k2.z + k2.w*k2.w
                 + k3.x*k3.x + k3.y*k3.y + k3.z*k3.z + k3.w*k3.w;
        s2 += __shfl_xor(s2, 16);
        s2 += __shfl_xor(s2, 32);
        U8 a0, a1;
        a0.b[0]=(__bf16)k0.x; a0.b[1]=(__bf16)k0.y; a0.b[2]=(__bf16)k0.z; a0.b[3]=(__bf16)k0.w;
        a0.b[4]=(__bf16)k1.x; a0.b[5]=(__bf16)k1.y; a0.b[6]=(__bf16)k1.z; a0.b[7]=(__bf16)k1.w;
        a1.b[0]=(__bf16)k2.x; a1.b[1]=(__bf16)k2.y; a1.b[2]=(__bf16)k2.z; a1.b[3]=(__bf16)k2.w;
        a1.b[4]=(__bf16)k3.x; a1.b[5]=(__bf16)k3.y; a1.b[6]=(__bf16)k3.z; a1.b[7]=(__bf16)k3.w;

        if (tt + 1 < ntiles) {
            const float* vs = vbase + (size_t)(tt + 1) * 65536;
            v0 = *(const float4*)(vs);
            v1 = *(const float4*)(vs + 4);
            v2 = *(const float4*)(vs + 8);
            v3 = *(const float4*)(vs + 12);
            const float* ks_ = kbase + (size_t)(tt + 1) * 65536;
            k0 = *(const float4*)(ks_);
            k1 = *(const float4*)(ks_ + 4);
            k2 = *(const float4*)(ks_ + 32);
            k3 = *(const float4*)(ks_ + 36);
        }

        // ---- S = K @ proj^T : fully register-resident B ----
        f32x4 sacc[16];
#pragma unroll
        for (int i = 0; i < 16; ++i) sacc[i] = (f32x4){0.f, 0.f, 0.f, 0.f};
#pragma unroll
        for (int ni = 0; ni < 16; ++ni)
            sacc[ni] = mfma16(a0.v, pb0r[ni], sacc[ni]);
#pragma unroll
        for (int ni = 0; ni < 16; ++ni)
            sacc[ni] = mfma16(a1.v, pb1r[ni], sacc[ni]);

        float pm[4];
#pragma unroll
        for (int r = 0; r < 4; ++r) {
            float m01 = fmaxf(sacc[0][r], sacc[1][r]);
#pragma unroll
            for (int ni = 2; ni < 16; ++ni) m01 = fmaxf(m01, sacc[ni][r]);
            pm[r] = m01;
        }
#pragma unroll
        for (int msk = 1; msk <= 8; msk <<= 1)
#pragma unroll
            for (int r = 0; r < 4; ++r)
                pm[r] = fmaxf(pm[r], __shfl_xor(pm[r], msk));
        float offv[4];
#pragma unroll
        for (int r = 0; r < 4; ++r) {
            float s2r = __shfl(s2, (lane & 48) + 4*hh + r);
            offv[r] = pm[r] + DN_SCALE * s2r;
        }

#pragma unroll
        for (int ni = 0; ni < 16; ++ni) {
            float e0 = __expf(sacc[ni][0] - offv[0]);
            float e1 = __expf(sacc[ni][1] - offv[1]);
            float e2 = __expf(sacc[ni][2] - offv[2]);
            float e3 = __expf(sacc[ni][3] - offv[3]);
            ksacc[ni] += e0 + e1 + e2 + e3;
            P4 pk;
            pk.b[0]=(__bf16)e0; pk.b[1]=(__bf16)e1; pk.b[2]=(__bf16)e2; pk.b[3]=(__bf16)e3;
            const int colp = (16*w + 4*hh) ^ (8*(ni & 7));
            *(uint2*)&kpT[16*ni + l15][colp] = pk.u2;
        }
        __syncthreads();   // B: kpT + VT ready (t+1 loads long since landed)

#pragma unroll
        for (int ks = 0; ks < 2; ++ks) {
            bf16x8 am[4], bv[4];
#pragma unroll
            for (int mi = 0; mi < 4; ++mi) {
                const int row = 64*w + 16*mi + l15;
                const int s = (4*w + mi) & 7;
                am[mi] = *(const bf16x8*)&kpT[row][8*((4*ks + hh) ^ s)];
            }
#pragma unroll
            for (int ni = 0; ni < 4; ++ni)
                bv[ni] = *(const bf16x8*)&VT[16*ni + l15][ks*32 + 8*hh];
#pragma unroll
            for (int mi = 0; mi < 4; ++mi)
#pragma unroll
                for (int ni = 0; ni < 4; ++ni)
                    cacc[mi][ni] = mfma16(am[mi], bv[ni], cacc[mi][ni]);
        }
    }

#pragma unroll
    for (int ni = 0; ni < 16; ++ni) {
        ksacc[ni] += __shfl_xor(ksacc[ni], 16);
        ksacc[ni] += __shfl_xor(ksacc[ni], 32);
    }
    __syncthreads();
    float* ksW = (float*)&VT[0][0];
    if (hh == 0) {
#pragma unroll
        for (int ni = 0; ni < 16; ++ni)
            ksW[w*256 + 16*ni + l15] = ksacc[ni];
    }
    __syncthreads();
    const int pc = blockIdx.x;
    if (tid < 256)
        ksum_part[(size_t)pc * 256 + tid] = ksW[tid] + ksW[256 + tid]
                                          + ksW[512 + tid] + ksW[768 + tid];
    float* cp = ctx_part + (size_t)pc * 256 * 64;
#pragma unroll
    for (int mi = 0; mi < 4; ++mi)
#pragma unroll
        for (int ni = 0; ni < 4; ++ni)
#pragma unroll
            for (int r = 0; r < 4; ++r)
                cp[(64*w + 16*mi + 4*hh + r) * 64 + 16*ni + l15] = cacc[mi][ni][r];
}

// ------------------------------------------------------------ reduce ------
// grid = 64 bh * 4 parts. Writes ctxT SWIZZLED: col = m ^ ((dh&7)<<3).
__global__ __launch_bounds__(256) void k_reduce(const float* __restrict__ ctx_part,
                                                const float* __restrict__ ksum_part,
                                                unsigned short* __restrict__ ctxT,
                                                float* __restrict__ ksum, int nchunk) {
    const int bh = blockIdx.x >> 2, part = blockIdx.x & 3;
    const int t = threadIdx.x;
    const int m = part*64 + (t & 63);
    const int dq = t >> 6;
    const float* cp = ctx_part + (size_t)bh * nchunk * 16384 + m*64 + dq*16;
    f32x4 s[4];
#pragma unroll
    for (int j = 0; j < 4; ++j) s[j] = *(const f32x4*)(cp + j*4);
    for (int c = 1; c < nchunk; ++c) {
        const float* cc = cp + (size_t)c * 16384;
#pragma unroll
        for (int j = 0; j < 4; ++j) {
            f32x4 a = *(const f32x4*)(cc + j*4);
            s[j] += a;
        }
    }
    unsigned short* ct = ctxT + (size_t)bh * 16384;
#pragma unroll
    for (int j = 0; j < 4; ++j)
#pragma unroll
        for (int e = 0; e < 4; ++e) {
            const int dh = dq*16 + j*4 + e;
            ct[dh * 256 + (m ^ ((dh & 7) << 3))] = f2bf(s[j][e]);
        }
    if (t < 64) {
        const int m2 = part*64 + t;
        const float* kp_ = ksum_part + (size_t)bh * nchunk * 256;
        float ks = 0.f;
        for (int c = 0; c < nchunk; ++c) ks += kp_[c*256 + m2];
        ksum[(size_t)bh * 256 + m2] = ks;
    }
}

// ------------------------------------------------------------- k_qout -----
// R12-proven: uL [4][16*128] two-phase m-halves; LDS 80KB -> 2 blocks/CU.
__global__ __launch_bounds__(256) void k_qout(const float* __restrict__ qg,
                                              const unsigned short* __restrict__ projs_swz,
                                              const unsigned short* __restrict__ ctxT,
                                              const float* __restrict__ ksum,
                                              unsigned short* __restrict__ attn) {
    const int bh = blockIdx.x >> 4, rg = blockIdx.x & 15;
    const int b = bh >> 4, h = bh & 15;
    const int tid = threadIdx.x;
    const int w = tid >> 6, lane = tid & 63, l15 = lane & 15, hh = lane >> 4;

    __shared__ __align__(16) unsigned short pjL[256 * 64];   // 32 KB
    __shared__ __align__(16) unsigned short ctxL[64 * 256];  // 32 KB
    __shared__ __align__(16) unsigned short uL[4][16 * 128]; // 16 KB

#pragma unroll
    for (int i = 0; i < 8; ++i) {
        const int blk = i*4 + w;
        gload16((const char*)projs_swz + blk*1024 + lane*16, (char*)pjL + blk*1024);
        gload16((const char*)(ctxT + (size_t)bh * 16384) + blk*1024 + lane*16,
                (char*)ctxL + blk*1024);
    }

    float ksr[16];
#pragma unroll
    for (int ni = 0; ni < 16; ++ni)
        ksr[ni] = ksum[(size_t)bh * 256 + 16*ni + l15];

    const float* qtile = qg + (size_t)(b*4096 + rg*256 + 16*w + l15) * 1024 + h*64 + hh*8;

    float4 qA[4], qB[4];
    qA[0] = *(const float4*)(qtile);
    qA[1] = *(const float4*)(qtile + 4);
    qA[2] = *(const float4*)(qtile + 32);
    qA[3] = *(const float4*)(qtile + 36);

    __syncthreads();   // pjL + ctxL ready (drains gload16)

#pragma unroll
    for (int t = 0; t < 4; ++t) {
        const float4* qc = (t & 1) ? qB : qA;
        float4*       qn = (t & 1) ? qA : qB;

        U8 a0, a1;
        a0.b[0]=(__bf16)qc[0].x; a0.b[1]=(__bf16)qc[0].y; a0.b[2]=(__bf16)qc[0].z; a0.b[3]=(__bf16)qc[0].w;
        a0.b[4]=(__bf16)qc[1].x; a0.b[5]=(__bf16)qc[1].y; a0.b[6]=(__bf16)qc[1].z; a0.b[7]=(__bf16)qc[1].w;
        a1.b[0]=(__bf16)qc[2].x; a1.b[1]=(__bf16)qc[2].y; a1.b[2]=(__bf16)qc[2].z; a1.b[3]=(__bf16)qc[2].w;
        a1.b[4]=(__bf16)qc[3].x; a1.b[5]=(__bf16)qc[3].y; a1.b[6]=(__bf16)qc[3].z; a1.b[7]=(__bf16)qc[3].w;

        if (t < 3) {
            const float* qs = qtile + (size_t)(t + 1) * 65536;
            qn[0] = *(const float4*)(qs);
            qn[1] = *(const float4*)(qs + 4);
            qn[2] = *(const float4*)(qs + 32);
            qn[3] = *(const float4*)(qs + 36);
        }

        // ---- S_q GEMM: B-frags from swizzled pjL ----
        f32x4 sacc[16];
#pragma unroll
        for (int i = 0; i < 16; ++i) sacc[i] = (f32x4){0.f, 0.f, 0.f, 0.f};
#pragma unroll
        for (int ni = 0; ni < 16; ++ni) {
            bf16x8 pb0 = *(const bf16x8*)&pjL[(16*ni + l15)*64 + ((8*hh) ^ ((l15 & 7) << 3))];
            sacc[ni] = mfma16(a0.v, pb0, sacc[ni]);
        }
#pragma unroll
        for (int ni = 0; ni < 16; ++ni) {
            bf16x8 pb1 = *(const bf16x8*)&pjL[(16*ni + l15)*64 + ((32 + 8*hh) ^ ((l15 & 7) << 3))];
            sacc[ni] = mfma16(a1.v, pb1, sacc[ni]);
        }

        float dp[4] = {0.f, 0.f, 0.f, 0.f};
        f32x4 nacc[4];
#pragma unroll
        for (int i = 0; i < 4; ++i) nacc[i] = (f32x4){0.f, 0.f, 0.f, 0.f};

        // ---- phase A: u=exp for ni 0-7 -> uL half; GEMM ks 0-3 ----
#pragma unroll
        for (int ni = 0; ni < 8; ++ni) {
#pragma unroll
            for (int r = 0; r < 4; ++r) {
                float e = __expf(sacc[ni][r]);
                dp[r] += e * ksr[ni];
                const int row = 4*hh + r;
                uL[w][row*128 + ((16*ni + l15) ^ ((row & 7) << 3))] = f2bf(e);
            }
        }
        asm volatile("s_waitcnt lgkmcnt(0)" ::: "memory");
        __builtin_amdgcn_sched_barrier(0);
#pragma unroll
        for (int ks = 0; ks < 4; ++ks) {
            bf16x8 a = *(const bf16x8*)&uL[w][l15*128 + ((ks*32 + 8*hh) ^ ((l15 & 7) << 3))];
#pragma unroll
            for (int ni = 0; ni < 4; ++ni) {
                bf16x8 bb = *(const bf16x8*)&ctxL[(16*ni + l15)*256
                                                  + ((ks*32 + 8*hh) ^ ((l15 & 7) << 3))];
                nacc[ni] = mfma16(a, bb, nacc[ni]);
            }
        }
        asm volatile("s_waitcnt lgkmcnt(0)" ::: "memory");
        __builtin_amdgcn_sched_barrier(0);

        // ---- phase B: u=exp for ni 8-15 -> uL half; GEMM ks 4-7 ----
#pragma unroll
        for (int ni = 8; ni < 16; ++ni) {
#pragma unroll
            for (int r = 0; r < 4; ++r) {
                float e = __expf(sacc[ni][r]);
                dp[r] += e * ksr[ni];
                const int row = 4*hh + r;
                uL[w][row*128 + ((16*(ni-8) + l15) ^ ((row & 7) << 3))] = f2bf(e);
            }
        }
        asm volatile("s_waitcnt lgkmcnt(0)" ::: "memory");
        __builtin_amdgcn_sched_barrier(0);
#pragma unroll
        for (int ks = 4; ks < 8; ++ks) {
            bf16x8 a = *(const bf16x8*)&uL[w][l15*128 + (((ks-4)*32 + 8*hh) ^ ((l15 & 7) << 3))];
#pragma unroll
            for (int ni = 0; ni < 4; ++ni) {
                bf16x8 bb = *(const bf16x8*)&ctxL[(16*ni + l15)*256
                                                  + ((ks*32 + 8*hh) ^ ((l15 & 7) << 3))];
                nacc[ni] = mfma16(a, bb, nacc[ni]);
            }
        }

        // ---- den reduce (in-wave) + epilogue ----
#pragma unroll
        for (int msk = 1; msk <= 8; msk <<= 1)
#pragma unroll
            for (int r = 0; r < 4; ++r)
                dp[r] += __shfl_xor(dp[r], msk);

#pragma unroll
        for (int r = 0; r < 4; ++r) {
            const float rd = 1.f / dp[r];
            const int grow = rg*256 + t*64 + 16*w + 4*hh + r;
            unsigned short* dst = attn + (size_t)(b*4096 + grow) * 1024 + h*64;
#pragma unroll
            for (int ni = 0; ni < 4; ++ni)
                dst[16*ni + l15] = f2bf(nacc[ni][r] * rd);
        }
        __builtin_amdgcn_sched_barrier(0);  // keep tile phases ordered
    }
}

// ------------------------------------------------------------ k_linear ----
// out[16384][1024] = attn_bf16 @ Wb^T + bias  (m97 structure, proven)
__global__ __launch_bounds__(256) void k_linear(const unsigned short* __restrict__ A,
                                                const unsigned short* __restrict__ Wb,
                                                const float* __restrict__ bias,
                                                float* __restrict__ out) {
    const int bm = blockIdx.x >> 3, bn = blockIdx.x & 7;
    const int tid = threadIdx.x;
    const int w = tid >> 6, lane = tid & 63, l15 = lane & 15, hh = lane >> 4;
    const int wm = w >> 1, wn = w & 1;
    const int m0 = bm * 128, n0 = bn * 128;

    __shared__ __align__(16) unsigned short As[128 * 64];
    __shared__ __align__(16) unsigned short Bs[128 * 64];

    const int srow = lane >> 3;
    const int scol = (lane & 7) * 8;

    f32x4 acc[4][4];
#pragma unroll
    for (int i = 0; i < 4; ++i)
#pragma unroll
        for (int j = 0; j < 4; ++j) acc[i][j] = (f32x4){0.f, 0.f, 0.f, 0.f};

    for (int kt = 0; kt < 16; ++kt) {
        __syncthreads();
#pragma unroll
        for (int i = 0; i < 4; ++i) {
            const int rr = (w*4 + i)*8 + srow;
            gload16(A  + (size_t)(m0 + rr) * 1024 + kt*64 + scol, &As[(w*4 + i) * 512]);
            gload16(Wb + (size_t)(n0 + rr) * 1024 + kt*64 + scol, &Bs[(w*4 + i) * 512]);
        }
        __syncthreads();
#pragma unroll
        for (int ks = 0; ks < 2; ++ks) {
            bf16x8 af[4], bw[4];
#pragma unroll
            for (int mi = 0; mi < 4; ++mi)
                af[mi] = *(const bf16x8*)&As[(wm*64 + 16*mi + l15) * 64 + ks*32 + 8*hh];
#pragma unroll
            for (int ni = 0; ni < 4; ++ni)
                bw[ni] = *(const bf16x8*)&Bs[(wn*64 + 16*ni + l15) * 64 + ks*32 + 8*hh];
#pragma unroll
            for (int mi = 0; mi < 4; ++mi)
#pragma unroll
                for (int ni = 0; ni < 4; ++ni)
                    acc[mi][ni] = mfma16(af[mi], bw[ni], acc[mi][ni]);
        }
    }

    float bs[4];
#pragma unroll
    for (int ni = 0; ni < 4; ++ni) bs[ni] = bias[n0 + wn*64 + 16*ni + l15];
#pragma unroll
    for (int mi = 0; mi < 4; ++mi) {
        const int row = m0 + wm*64 + 16*mi + 4*hh;
#pragma unroll
        for (int r = 0; r < 4; ++r) {
            float* o = out + (size_t)(row + r) * 1024 + n0 + wn*64;
#pragma unroll
            for (int ni = 0; ni < 4; ++ni)
                o[16*ni + l15] = acc[mi][ni][r] + bs[ni];
        }
    }
}

// ------------------------------------------------------------ launch ------
extern "C" void kernel_launch(void* const* d_in, const int* in_sizes, int n_in,
                              void* d_out, int out_size, void* d_ws, size_t ws_size,
                              hipStream_t stream) {
    const float* q    = (const float*)d_in[0];
    const float* k    = (const float*)d_in[1];
    const float* v    = (const float*)d_in[2];
    const float* W    = (const float*)d_in[3];
    const float* bias = (const float*)d_in[4];
    const float* proj = (const float*)d_in[5];
    float* out = (float*)d_out;

    // nchunk=8 (R9-proven)
    int nchunk = 8;
    while (nchunk > 4) {
        size_t need = 33554432ull + 2097152 + 2097152 + 65536 + 32768 + 32768
                    + (size_t)nchunk * 65536
                    + (size_t)nchunk * 4194304
                    + 4096;
        if (need <= ws_size) break;
        nchunk >>= 1;
    }
    const int cshift = (nchunk == 8) ? 3 : 2;
    const int ntiles = 64 / nchunk;

    char* ws = (char*)d_ws;
    size_t off = 0;
    unsigned short* attn  = (unsigned short*)(ws + off); off += 33554432;
    unsigned short* ctxT  = (unsigned short*)(ws + off); off += 2097152;
    unsigned short* Wb    = (unsigned short*)(ws + off); off += 2097152;
    float*          ksum  = (float*)(ws + off);          off += 65536;
    unsigned short* projs = (unsigned short*)(ws + off); off += 32768;
    unsigned short* projz = (unsigned short*)(ws + off); off += 32768;
    float*          ksump = (float*)(ws + off);          off += (size_t)nchunk * 65536;
    float*          ctxp  = (float*)(ws + off);          off += (size_t)nchunk * 4194304;

    k_prep<<<dim3(4096), dim3(256), 0, stream>>>(W, proj, Wb, projs, projz);
    k_ctx<<<dim3(64 * nchunk), dim3(256), 0, stream>>>(k, v, projs, ctxp, ksump,
                                                       cshift, ntiles);
    k_reduce<<<dim3(256), dim3(256), 0, stream>>>(ctxp, ksump, ctxT, ksum, nchunk);
    k_qout<<<dim3(1024), dim3(256), 0, stream>>>(q, projz, ctxT, ksum, attn);
    k_linear<<<dim3(1024), dim3(256), 0, stream>>>(attn, Wb, bias, out);
}

// Round 14
// 172.630 us; speedup vs baseline: 1.0437x; 1.0437x over previous
//
#include <hip/hip_runtime.h>
#include <hip/hip_bf16.h>
#include <stdint.h>

// Problem constants: B=4, N=4096, D=1024, H=16, M=256, DH=64
#define DATA_SCALE 0.35355339059327373f  // 64^-0.25
#define DN_SCALE   0.0625f               // 0.5 * 64^-0.5

typedef __bf16 bf16x8 __attribute__((ext_vector_type(8)));
typedef float  f32x4  __attribute__((ext_vector_type(4)));

static __device__ __forceinline__ unsigned short f2bf(float f) {
    union { __bf16 b; unsigned short u; } t;
    t.b = (__bf16)f;
    return t.u;
}

static __device__ __forceinline__ f32x4 mfma16(bf16x8 a, bf16x8 b, f32x4 c) {
    return __builtin_amdgcn_mfma_f32_16x16x32_bf16(a, b, c, 0, 0, 0);
}

static __device__ __forceinline__ void gload16(const void* g, void* lds) {
    __builtin_amdgcn_global_load_lds(
        (const __attribute__((address_space(1))) unsigned int*)g,
        (__attribute__((address_space(3))) unsigned int*)lds, 16, 0, 0);
}

union U8 { unsigned short s[8]; __bf16 b[8]; bf16x8 v; };
union P4 { __bf16 b[4]; uint2 u2; };

// ---------------------------------------------------------------- prep ----
__global__ __launch_bounds__(256) void k_prep(const float* __restrict__ W,
                                              const float* __restrict__ proj,
                                              unsigned short* __restrict__ Wb,
                                              unsigned short* __restrict__ projs,
                                              unsigned short* __restrict__ projs_swz) {
    int i = blockIdx.x * 256 + threadIdx.x;
    if (i < 1024 * 1024) Wb[i] = f2bf(W[i]);
    if (i < 256 * 64) {
        const int row = i >> 6, col = i & 63;
        unsigned short v = f2bf(proj[i] * DATA_SCALE);
        projs[i] = v;
        projs_swz[row * 64 + (col ^ ((row & 7) << 3))] = v;
    }
}

// ------------------------------------------------------------- k_ctx ------
// R12-proven config (best k_ctx: 71us): nchunk=8, K/V reg-prefetch,
// ks=0 proj frags hoisted (VGPR 184, no spill), ks=1 from pjL.
// R13's full hoist (VGPR 216) regressed — reverted.
__global__ __launch_bounds__(256) void k_ctx(const float* __restrict__ kg,
                                             const float* __restrict__ vg,
                                             const unsigned short* __restrict__ projs,
                                             const unsigned short* __restrict__ projz,
                                             float* __restrict__ ctx_part,
                                             float* __restrict__ ksum_part,
                                             int cshift, int ntiles) {
    const int bh = blockIdx.x >> cshift, chunk = blockIdx.x & ((1 << cshift) - 1);
    const int b = bh >> 4, h = bh & 15;
    const int tid = threadIdx.x;
    const int w = tid >> 6, lane = tid & 63, l15 = lane & 15, hh = lane >> 4;

    __shared__ __align__(16) unsigned short kpT[256][72];
    __shared__ __align__(16) unsigned short VT[64][72];
    __shared__ __align__(16) unsigned short pjL[256 * 64];   // swizzled proj

#pragma unroll
    for (int i = 0; i < 8; ++i) {
        const int blk = i*4 + w;
        gload16((const char*)projz + blk*1024 + lane*16, (char*)pjL + blk*1024);
    }

    // ---- hoist ks=0 proj B-fragments (loop-invariant, from linear projs) --
    bf16x8 pb0r[16];
#pragma unroll
    for (int ni = 0; ni < 16; ++ni)
        pb0r[ni] = *(const bf16x8*)(projs + (size_t)(16*ni + l15) * 64 + 8*hh);

    f32x4 cacc[4][4];
#pragma unroll
    for (int i = 0; i < 4; ++i)
#pragma unroll
        for (int j = 0; j < 4; ++j) cacc[i][j] = (f32x4){0.f, 0.f, 0.f, 0.f};
    float ksacc[16];
#pragma unroll
    for (int i = 0; i < 16; ++i) ksacc[i] = 0.f;

    const size_t rowoff = (size_t)(b * 4096 + chunk * ntiles * 64) * 1024 + h * 64;

    const float* vbase = vg + rowoff + (size_t)lane * 1024 + w * 16;
    const float* kbase = kg + rowoff + (size_t)(16*w + l15) * 1024 + hh * 8;

    float4 v0 = *(const float4*)(vbase);
    float4 v1 = *(const float4*)(vbase + 4);
    float4 v2 = *(const float4*)(vbase + 8);
    float4 v3 = *(const float4*)(vbase + 12);
    float4 k0 = *(const float4*)(kbase);
    float4 k1 = *(const float4*)(kbase + 4);
    float4 k2 = *(const float4*)(kbase + 32);
    float4 k3 = *(const float4*)(kbase + 36);

    for (int tt = 0; tt < ntiles; ++tt) {
        __syncthreads();   // A: prev tile's kpT/VT reads done; (tt=0: pjL ready)

        {
            const int n = lane, cs = w * 16;
            VT[cs+ 0][n] = f2bf(v0.x); VT[cs+ 1][n] = f2bf(v0.y);
            VT[cs+ 2][n] = f2bf(v0.z); VT[cs+ 3][n] = f2bf(v0.w);
            VT[cs+ 4][n] = f2bf(v1.x); VT[cs+ 5][n] = f2bf(v1.y);
            VT[cs+ 6][n] = f2bf(v1.z); VT[cs+ 7][n] = f2bf(v1.w);
            VT[cs+ 8][n] = f2bf(v2.x); VT[cs+ 9][n] = f2bf(v2.y);
            VT[cs+10][n] = f2bf(v2.z); VT[cs+11][n] = f2bf(v2.w);
            VT[cs+12][n] = f2bf(v3.x); VT[cs+13][n] = f2bf(v3.y);
            VT[cs+14][n] = f2bf(v3.z); VT[cs+15][n] = f2bf(v3.w);
        }

        float s2 = k0.x*k0.x + k0.y*k0.y + k0.z*k0.z + k0.w*k0.w
                 + k1.x*k1.x + k1.y*k1.y + k1.z*k1.z + k1.w*k1.w
                 + k2.x*k2.x + k2.y*k2.y + k2.z*k2.z + k2.w*k2.w
                 + k3.x*k3.x + k3.y*k3.y + k3.z*k3.z + k3.w*k3.w;
        s2 += __shfl_xor(s2, 16);
        s2 += __shfl_xor(s2, 32);
        U8 a0, a1;
        a0.b[0]=(__bf16)k0.x; a0.b[1]=(__bf16)k0.y; a0.b[2]=(__bf16)k0.z; a0.b[3]=(__bf16)k0.w;
        a0.b[4]=(__bf16)k1.x; a0.b[5]=(__bf16)k1.y; a0.b[6]=(__bf16)k1.z; a0.b[7]=(__bf16)k1.w;
        a1.b[0]=(__bf16)k2.x; a1.b[1]=(__bf16)k2.y; a1.b[2]=(__bf16)k2.z; a1.b[3]=(__bf16)k2.w;
        a1.b[4]=(__bf16)k3.x; a1.b[5]=(__bf16)k3.y; a1.b[6]=(__bf16)k3.z; a1.b[7]=(__bf16)k3.w;

        if (tt + 1 < ntiles) {
            const float* vs = vbase + (size_t)(tt + 1) * 65536;
            v0 = *(const float4*)(vs);
            v1 = *(const float4*)(vs + 4);
            v2 = *(const float4*)(vs + 8);
            v3 = *(const float4*)(vs + 12);
            const float* ks_ = kbase + (size_t)(tt + 1) * 65536;
            k0 = *(const float4*)(ks_);
            k1 = *(const float4*)(ks_ + 4);
            k2 = *(const float4*)(ks_ + 32);
            k3 = *(const float4*)(ks_ + 36);
        }

        // ---- S = K @ proj^T : ks=0 all-register, ks=1 from pjL ----
        f32x4 sacc[16];
#pragma unroll
        for (int i = 0; i < 16; ++i) sacc[i] = (f32x4){0.f, 0.f, 0.f, 0.f};
#pragma unroll
        for (int ni = 0; ni < 16; ++ni)
            sacc[ni] = mfma16(a0.v, pb0r[ni], sacc[ni]);
#pragma unroll
        for (int ni = 0; ni < 16; ++ni) {
            bf16x8 pb1 = *(const bf16x8*)&pjL[(16*ni + l15)*64 + ((32 + 8*hh) ^ ((l15 & 7) << 3))];
            sacc[ni] = mfma16(a1.v, pb1, sacc[ni]);
        }

        float pm[4];
#pragma unroll
        for (int r = 0; r < 4; ++r) {
            float m01 = fmaxf(sacc[0][r], sacc[1][r]);
#pragma unroll
            for (int ni = 2; ni < 16; ++ni) m01 = fmaxf(m01, sacc[ni][r]);
            pm[r] = m01;
        }
#pragma unroll
        for (int msk = 1; msk <= 8; msk <<= 1)
#pragma unroll
            for (int r = 0; r < 4; ++r)
                pm[r] = fmaxf(pm[r], __shfl_xor(pm[r], msk));
        float offv[4];
#pragma unroll
        for (int r = 0; r < 4; ++r) {
            float s2r = __shfl(s2, (lane & 48) + 4*hh + r);
            offv[r] = pm[r] + DN_SCALE * s2r;
        }

#pragma unroll
        for (int ni = 0; ni < 16; ++ni) {
            float e0 = __expf(sacc[ni][0] - offv[0]);
            float e1 = __expf(sacc[ni][1] - offv[1]);
            float e2 = __expf(sacc[ni][2] - offv[2]);
            float e3 = __expf(sacc[ni][3] - offv[3]);
            ksacc[ni] += e0 + e1 + e2 + e3;
            P4 pk;
            pk.b[0]=(__bf16)e0; pk.b[1]=(__bf16)e1; pk.b[2]=(__bf16)e2; pk.b[3]=(__bf16)e3;
            const int colp = (16*w + 4*hh) ^ (8*(ni & 7));
            *(uint2*)&kpT[16*ni + l15][colp] = pk.u2;
        }
        __syncthreads();   // B: kpT + VT ready (t+1 loads long since landed)

#pragma unroll
        for (int ks = 0; ks < 2; ++ks) {
            bf16x8 am[4], bv[4];
#pragma unroll
            for (int mi = 0; mi < 4; ++mi) {
                const int row = 64*w + 16*mi + l15;
                const int s = (4*w + mi) & 7;
                am[mi] = *(const bf16x8*)&kpT[row][8*((4*ks + hh) ^ s)];
            }
#pragma unroll
            for (int ni = 0; ni < 4; ++ni)
                bv[ni] = *(const bf16x8*)&VT[16*ni + l15][ks*32 + 8*hh];
#pragma unroll
            for (int mi = 0; mi < 4; ++mi)
#pragma unroll
                for (int ni = 0; ni < 4; ++ni)
                    cacc[mi][ni] = mfma16(am[mi], bv[ni], cacc[mi][ni]);
        }
    }

#pragma unroll
    for (int ni = 0; ni < 16; ++ni) {
        ksacc[ni] += __shfl_xor(ksacc[ni], 16);
        ksacc[ni] += __shfl_xor(ksacc[ni], 32);
    }
    __syncthreads();
    float* ksW = (float*)&VT[0][0];
    if (hh == 0) {
#pragma unroll
        for (int ni = 0; ni < 16; ++ni)
            ksW[w*256 + 16*ni + l15] = ksacc[ni];
    }
    __syncthreads();
    const int pc = blockIdx.x;
    if (tid < 256)
        ksum_part[(size_t)pc * 256 + tid] = ksW[tid] + ksW[256 + tid]
                                          + ksW[512 + tid] + ksW[768 + tid];
    float* cp = ctx_part + (size_t)pc * 256 * 64;
#pragma unroll
    for (int mi = 0; mi < 4; ++mi)
#pragma unroll
        for (int ni = 0; ni < 4; ++ni)
#pragma unroll
            for (int r = 0; r < 4; ++r)
                cp[(64*w + 16*mi + 4*hh + r) * 64 + 16*ni + l15] = cacc[mi][ni][r];
}

// ------------------------------------------------------------ reduce ------
// grid = 64 bh * 4 parts. Writes ctxT SWIZZLED: col = m ^ ((dh&7)<<3).
__global__ __launch_bounds__(256) void k_reduce(const float* __restrict__ ctx_part,
                                                const float* __restrict__ ksum_part,
                                                unsigned short* __restrict__ ctxT,
                                                float* __restrict__ ksum, int nchunk) {
    const int bh = blockIdx.x >> 2, part = blockIdx.x & 3;
    const int t = threadIdx.x;
    const int m = part*64 + (t & 63);
    const int dq = t >> 6;
    const float* cp = ctx_part + (size_t)bh * nchunk * 16384 + m*64 + dq*16;
    f32x4 s[4];
#pragma unroll
    for (int j = 0; j < 4; ++j) s[j] = *(const f32x4*)(cp + j*4);
    for (int c = 1; c < nchunk; ++c) {
        const float* cc = cp + (size_t)c * 16384;
#pragma unroll
        for (int j = 0; j < 4; ++j) {
            f32x4 a = *(const f32x4*)(cc + j*4);
            s[j] += a;
        }
    }
    unsigned short* ct = ctxT + (size_t)bh * 16384;
#pragma unroll
    for (int j = 0; j < 4; ++j)
#pragma unroll
        for (int e = 0; e < 4; ++e) {
            const int dh = dq*16 + j*4 + e;
            ct[dh * 256 + (m ^ ((dh & 7) << 3))] = f2bf(s[j][e]);
        }
    if (t < 64) {
        const int m2 = part*64 + t;
        const float* kp_ = ksum_part + (size_t)bh * nchunk * 256;
        float ks = 0.f;
        for (int c = 0; c < nchunk; ++c) ks += kp_[c*256 + m2];
        ksum[(size_t)bh * 256 + m2] = ks;
    }
}

// ------------------------------------------------------------- k_qout -----
// R12-proven + R14 XCD swizzle: the 16 rg-blocks sharing one bh's
// ctxT/pjL now land on the SAME XCD (T1; grid 1024 % 8 == 0, bijective).
__global__ __launch_bounds__(256) void k_qout(const float* __restrict__ qg,
                                              const unsigned short* __restrict__ projs_swz,
                                              const unsigned short* __restrict__ ctxT,
                                              const float* __restrict__ ksum,
                                              unsigned short* __restrict__ attn) {
    const int lb = (blockIdx.x & 7) * 128 + (blockIdx.x >> 3);   // XCD swizzle
    const int bh = lb >> 4, rg = lb & 15;
    const int b = bh >> 4, h = bh & 15;
    const int tid = threadIdx.x;
    const int w = tid >> 6, lane = tid & 63, l15 = lane & 15, hh = lane >> 4;

    __shared__ __align__(16) unsigned short pjL[256 * 64];   // 32 KB
    __shared__ __align__(16) unsigned short ctxL[64 * 256];  // 32 KB
    __shared__ __align__(16) unsigned short uL[4][16 * 128]; // 16 KB

#pragma unroll
    for (int i = 0; i < 8; ++i) {
        const int blk = i*4 + w;
        gload16((const char*)projs_swz + blk*1024 + lane*16, (char*)pjL + blk*1024);
        gload16((const char*)(ctxT + (size_t)bh * 16384) + blk*1024 + lane*16,
                (char*)ctxL + blk*1024);
    }

    float ksr[16];
#pragma unroll
    for (int ni = 0; ni < 16; ++ni)
        ksr[ni] = ksum[(size_t)bh * 256 + 16*ni + l15];

    const float* qtile = qg + (size_t)(b*4096 + rg*256 + 16*w + l15) * 1024 + h*64 + hh*8;

    float4 qA[4], qB[4];
    qA[0] = *(const float4*)(qtile);
    qA[1] = *(const float4*)(qtile + 4);
    qA[2] = *(const float4*)(qtile + 32);
    qA[3] = *(const float4*)(qtile + 36);

    __syncthreads();   // pjL + ctxL ready (drains gload16)

#pragma unroll
    for (int t = 0; t < 4; ++t) {
        const float4* qc = (t & 1) ? qB : qA;
        float4*       qn = (t & 1) ? qA : qB;

        U8 a0, a1;
        a0.b[0]=(__bf16)qc[0].x; a0.b[1]=(__bf16)qc[0].y; a0.b[2]=(__bf16)qc[0].z; a0.b[3]=(__bf16)qc[0].w;
        a0.b[4]=(__bf16)qc[1].x; a0.b[5]=(__bf16)qc[1].y; a0.b[6]=(__bf16)qc[1].z; a0.b[7]=(__bf16)qc[1].w;
        a1.b[0]=(__bf16)qc[2].x; a1.b[1]=(__bf16)qc[2].y; a1.b[2]=(__bf16)qc[2].z; a1.b[3]=(__bf16)qc[2].w;
        a1.b[4]=(__bf16)qc[3].x; a1.b[5]=(__bf16)qc[3].y; a1.b[6]=(__bf16)qc[3].z; a1.b[7]=(__bf16)qc[3].w;

        if (t < 3) {
            const float* qs = qtile + (size_t)(t + 1) * 65536;
            qn[0] = *(const float4*)(qs);
            qn[1] = *(const float4*)(qs + 4);
            qn[2] = *(const float4*)(qs + 32);
            qn[3] = *(const float4*)(qs + 36);
        }

        // ---- S_q GEMM: B-frags from swizzled pjL ----
        f32x4 sacc[16];
#pragma unroll
        for (int i = 0; i < 16; ++i) sacc[i] = (f32x4){0.f, 0.f, 0.f, 0.f};
#pragma unroll
        for (int ni = 0; ni < 16; ++ni) {
            bf16x8 pb0 = *(const bf16x8*)&pjL[(16*ni + l15)*64 + ((8*hh) ^ ((l15 & 7) << 3))];
            sacc[ni] = mfma16(a0.v, pb0, sacc[ni]);
        }
#pragma unroll
        for (int ni = 0; ni < 16; ++ni) {
            bf16x8 pb1 = *(const bf16x8*)&pjL[(16*ni + l15)*64 + ((32 + 8*hh) ^ ((l15 & 7) << 3))];
            sacc[ni] = mfma16(a1.v, pb1, sacc[ni]);
        }

        float dp[4] = {0.f, 0.f, 0.f, 0.f};
        f32x4 nacc[4];
#pragma unroll
        for (int i = 0; i < 4; ++i) nacc[i] = (f32x4){0.f, 0.f, 0.f, 0.f};

        // ---- phase A: u=exp for ni 0-7 -> uL half; GEMM ks 0-3 ----
#pragma unroll
        for (int ni = 0; ni < 8; ++ni) {
#pragma unroll
            for (int r = 0; r < 4; ++r) {
                float e = __expf(sacc[ni][r]);
                dp[r] += e * ksr[ni];
                const int row = 4*hh + r;
                uL[w][row*128 + ((16*ni + l15) ^ ((row & 7) << 3))] = f2bf(e);
            }
        }
        asm volatile("s_waitcnt lgkmcnt(0)" ::: "memory");
        __builtin_amdgcn_sched_barrier(0);
#pragma unroll
        for (int ks = 0; ks < 4; ++ks) {
            bf16x8 a = *(const bf16x8*)&uL[w][l15*128 + ((ks*32 + 8*hh) ^ ((l15 & 7) << 3))];
#pragma unroll
            for (int ni = 0; ni < 4; ++ni) {
                bf16x8 bb = *(const bf16x8*)&ctxL[(16*ni + l15)*256
                                                  + ((ks*32 + 8*hh) ^ ((l15 & 7) << 3))];
                nacc[ni] = mfma16(a, bb, nacc[ni]);
            }
        }
        asm volatile("s_waitcnt lgkmcnt(0)" ::: "memory");
        __builtin_amdgcn_sched_barrier(0);

        // ---- phase B: u=exp for ni 8-15 -> uL half; GEMM ks 4-7 ----
#pragma unroll
        for (int ni = 8; ni < 16; ++ni) {
#pragma unroll
            for (int r = 0; r < 4; ++r) {
                float e = __expf(sacc[ni][r]);
                dp[r] += e * ksr[ni];
                const int row = 4*hh + r;
                uL[w][row*128 + ((16*(ni-8) + l15) ^ ((row & 7) << 3))] = f2bf(e);
            }
        }
        asm volatile("s_waitcnt lgkmcnt(0)" ::: "memory");
        __builtin_amdgcn_sched_barrier(0);
#pragma unroll
        for (int ks = 4; ks < 8; ++ks) {
            bf16x8 a = *(const bf16x8*)&uL[w][l15*128 + (((ks-4)*32 + 8*hh) ^ ((l15 & 7) << 3))];
#pragma unroll
            for (int ni = 0; ni < 4; ++ni) {
                bf16x8 bb = *(const bf16x8*)&ctxL[(16*ni + l15)*256
                                                  + ((ks*32 + 8*hh) ^ ((l15 & 7) << 3))];
                nacc[ni] = mfma16(a, bb, nacc[ni]);
            }
        }

        // ---- den reduce (in-wave) + epilogue ----
#pragma unroll
        for (int msk = 1; msk <= 8; msk <<= 1)
#pragma unroll
            for (int r = 0; r < 4; ++r)
                dp[r] += __shfl_xor(dp[r], msk);

#pragma unroll
        for (int r = 0; r < 4; ++r) {
            const float rd = 1.f / dp[r];
            const int grow = rg*256 + t*64 + 16*w + 4*hh + r;
            unsigned short* dst = attn + (size_t)(b*4096 + grow) * 1024 + h*64;
#pragma unroll
            for (int ni = 0; ni < 4; ++ni)
                dst[16*ni + l15] = f2bf(nacc[ni][r] * rd);
        }
        __builtin_amdgcn_sched_barrier(0);  // keep tile phases ordered
    }
}

// ------------------------------------------------------------ k_linear ----
// m97 structure + R14 XCD swizzle: the 8 bn-blocks sharing one bm's A-tile
// now land on the SAME XCD (A-tile fetched once per L2, not 8x).
__global__ __launch_bounds__(256) void k_linear(const unsigned short* __restrict__ A,
                                                const unsigned short* __restrict__ Wb,
                                                const float* __restrict__ bias,
                                                float* __restrict__ out) {
    const int lb = (blockIdx.x & 7) * 128 + (blockIdx.x >> 3);   // XCD swizzle
    const int bm = lb >> 3, bn = lb & 7;
    const int tid = threadIdx.x;
    const int w = tid >> 6, lane = tid & 63, l15 = lane & 15, hh = lane >> 4;
    const int wm = w >> 1, wn = w & 1;
    const int m0 = bm * 128, n0 = bn * 128;

    __shared__ __align__(16) unsigned short As[128 * 64];
    __shared__ __align__(16) unsigned short Bs[128 * 64];

    const int srow = lane >> 3;
    const int scol = (lane & 7) * 8;

    f32x4 acc[4][4];
#pragma unroll
    for (int i = 0; i < 4; ++i)
#pragma unroll
        for (int j = 0; j < 4; ++j) acc[i][j] = (f32x4){0.f, 0.f, 0.f, 0.f};

    for (int kt = 0; kt < 16; ++kt) {
        __syncthreads();
#pragma unroll
        for (int i = 0; i < 4; ++i) {
            const int rr = (w*4 + i)*8 + srow;
            gload16(A  + (size_t)(m0 + rr) * 1024 + kt*64 + scol, &As[(w*4 + i) * 512]);
            gload16(Wb + (size_t)(n0 + rr) * 1024 + kt*64 + scol, &Bs[(w*4 + i) * 512]);
        }
        __syncthreads();
#pragma unroll
        for (int ks = 0; ks < 2; ++ks) {
            bf16x8 af[4], bw[4];
#pragma unroll
            for (int mi = 0; mi < 4; ++mi)
                af[mi] = *(const bf16x8*)&As[(wm*64 + 16*mi + l15) * 64 + ks*32 + 8*hh];
#pragma unroll
            for (int ni = 0; ni < 4; ++ni)
                bw[ni] = *(const bf16x8*)&Bs[(wn*64 + 16*ni + l15) * 64 + ks*32 + 8*hh];
#pragma unroll
            for (int mi = 0; mi < 4; ++mi)
#pragma unroll
                for (int ni = 0; ni < 4; ++ni)
                    acc[mi][ni] = mfma16(af[mi], bw[ni], acc[mi][ni]);
        }
    }

    float bs[4];
#pragma unroll
    for (int ni = 0; ni < 4; ++ni) bs[ni] = bias[n0 + wn*64 + 16*ni + l15];
#pragma unroll
    for (int mi = 0; mi < 4; ++mi) {
        const int row = m0 + wm*64 + 16*mi + 4*hh;
#pragma unroll
        for (int r = 0; r < 4; ++r) {
            float* o = out + (size_t)(row + r) * 1024 + n0 + wn*64;
#pragma unroll
            for (int ni = 0; ni < 4; ++ni)
                o[16*ni + l15] = acc[mi][ni][r] + bs[ni];
        }
    }
}

// ------------------------------------------------------------ launch ------
extern "C" void kernel_launch(void* const* d_in, const int* in_sizes, int n_in,
                              void* d_out, int out_size, void* d_ws, size_t ws_size,
                              hipStream_t stream) {
    const float* q    = (const float*)d_in[0];
    const float* k    = (const float*)d_in[1];
    const float* v    = (const float*)d_in[2];
    const float* W    = (const float*)d_in[3];
    const float* bias = (const float*)d_in[4];
    const float* proj = (const float*)d_in[5];
    float* out = (float*)d_out;

    // nchunk=8 (R9/R12-proven)
    int nchunk = 8;
    while (nchunk > 4) {
        size_t need = 33554432ull + 2097152 + 2097152 + 65536 + 32768 + 32768
                    + (size_t)nchunk * 65536
                    + (size_t)nchunk * 4194304
                    + 4096;
        if (need <= ws_size) break;
        nchunk >>= 1;
    }
    const int cshift = (nchunk == 8) ? 3 : 2;
    const int ntiles = 64 / nchunk;

    char* ws = (char*)d_ws;
    size_t off = 0;
    unsigned short* attn  = (unsigned short*)(ws + off); off += 33554432;
    unsigned short* ctxT  = (unsigned short*)(ws + off); off += 2097152;
    unsigned short* Wb    = (unsigned short*)(ws + off); off += 2097152;
    float*          ksum  = (float*)(ws + off);          off += 65536;
    unsigned short* projs = (unsigned short*)(ws + off); off += 32768;
    unsigned short* projz = (unsigned short*)(ws + off); off += 32768;
    float*          ksump = (float*)(ws + off);          off += (size_t)nchunk * 65536;
    float*          ctxp  = (float*)(ws + off);          off += (size_t)nchunk * 4194304;

    k_prep<<<dim3(4096), dim3(256), 0, stream>>>(W, proj, Wb, projs, projz);
    k_ctx<<<dim3(64 * nchunk), dim3(256), 0, stream>>>(k, v, projs, projz, ctxp, ksump,
                                                       cshift, ntiles);
    k_reduce<<<dim3(256), dim3(256), 0, stream>>>(ctxp, ksump, ctxT, ksum, nchunk);
    k_qout<<<dim3(1024), dim3(256), 0, stream>>>(q, projz, ctxT, ksum, attn);
    k_linear<<<dim3(1024), dim3(256), 0, stream>>>(attn, Wb, bias, out);
}

// Round 15
// 171.048 us; speedup vs baseline: 1.0534x; 1.0092x over previous
//
#include <hip/hip_runtime.h>
#include <hip/hip_bf16.h>
#include <stdint.h>

// Problem constants: B=4, N=4096, D=1024, H=16, M=256, DH=64
#define DATA_SCALE 0.35355339059327373f  // 64^-0.25
#define DN_SCALE   0.0625f               // 0.5 * 64^-0.5

typedef __bf16 bf16x8 __attribute__((ext_vector_type(8)));
typedef float  f32x4  __attribute__((ext_vector_type(4)));

static __device__ __forceinline__ unsigned short f2bf(float f) {
    union { __bf16 b; unsigned short u; } t;
    t.b = (__bf16)f;
    return t.u;
}

static __device__ __forceinline__ f32x4 mfma16(bf16x8 a, bf16x8 b, f32x4 c) {
    return __builtin_amdgcn_mfma_f32_16x16x32_bf16(a, b, c, 0, 0, 0);
}

static __device__ __forceinline__ void gload16(const void* g, void* lds) {
    __builtin_amdgcn_global_load_lds(
        (const __attribute__((address_space(1))) unsigned int*)g,
        (__attribute__((address_space(3))) unsigned int*)lds, 16, 0, 0);
}

union U8 { unsigned short s[8]; __bf16 b[8]; bf16x8 v; };
union P4 { __bf16 b[4]; uint2 u2; };

// ---------------------------------------------------------------- prep ----
__global__ __launch_bounds__(256) void k_prep(const float* __restrict__ W,
                                              const float* __restrict__ proj,
                                              unsigned short* __restrict__ Wb,
                                              unsigned short* __restrict__ projs,
                                              unsigned short* __restrict__ projs_swz) {
    int i = blockIdx.x * 256 + threadIdx.x;
    if (i < 1024 * 1024) Wb[i] = f2bf(W[i]);
    if (i < 256 * 64) {
        const int row = i >> 6, col = i & 63;
        unsigned short v = f2bf(proj[i] * DATA_SCALE);
        projs[i] = v;
        projs_swz[row * 64 + (col ^ ((row & 7) << 3))] = v;
    }
}

// ------------------------------------------------------------- k_ctx ------
// R12-proven config (best k_ctx: ~70us): nchunk=8, K/V reg-prefetch,
// ks=0 proj frags hoisted (VGPR 184, no spill), ks=1 from pjL.
__global__ __launch_bounds__(256) void k_ctx(const float* __restrict__ kg,
                                             const float* __restrict__ vg,
                                             const unsigned short* __restrict__ projs,
                                             const unsigned short* __restrict__ projz,
                                             float* __restrict__ ctx_part,
                                             float* __restrict__ ksum_part,
                                             int cshift, int ntiles) {
    const int bh = blockIdx.x >> cshift, chunk = blockIdx.x & ((1 << cshift) - 1);
    const int b = bh >> 4, h = bh & 15;
    const int tid = threadIdx.x;
    const int w = tid >> 6, lane = tid & 63, l15 = lane & 15, hh = lane >> 4;

    __shared__ __align__(16) unsigned short kpT[256][72];
    __shared__ __align__(16) unsigned short VT[64][72];
    __shared__ __align__(16) unsigned short pjL[256 * 64];   // swizzled proj

#pragma unroll
    for (int i = 0; i < 8; ++i) {
        const int blk = i*4 + w;
        gload16((const char*)projz + blk*1024 + lane*16, (char*)pjL + blk*1024);
    }

    // ---- hoist ks=0 proj B-fragments (loop-invariant, from linear projs) --
    bf16x8 pb0r[16];
#pragma unroll
    for (int ni = 0; ni < 16; ++ni)
        pb0r[ni] = *(const bf16x8*)(projs + (size_t)(16*ni + l15) * 64 + 8*hh);

    f32x4 cacc[4][4];
#pragma unroll
    for (int i = 0; i < 4; ++i)
#pragma unroll
        for (int j = 0; j < 4; ++j) cacc[i][j] = (f32x4){0.f, 0.f, 0.f, 0.f};
    float ksacc[16];
#pragma unroll
    for (int i = 0; i < 16; ++i) ksacc[i] = 0.f;

    const size_t rowoff = (size_t)(b * 4096 + chunk * ntiles * 64) * 1024 + h * 64;

    const float* vbase = vg + rowoff + (size_t)lane * 1024 + w * 16;
    const float* kbase = kg + rowoff + (size_t)(16*w + l15) * 1024 + hh * 8;

    float4 v0 = *(const float4*)(vbase);
    float4 v1 = *(const float4*)(vbase + 4);
    float4 v2 = *(const float4*)(vbase + 8);
    float4 v3 = *(const float4*)(vbase + 12);
    float4 k0 = *(const float4*)(kbase);
    float4 k1 = *(const float4*)(kbase + 4);
    float4 k2 = *(const float4*)(kbase + 32);
    float4 k3 = *(const float4*)(kbase + 36);

    for (int tt = 0; tt < ntiles; ++tt) {
        __syncthreads();   // A: prev tile's kpT/VT reads done; (tt=0: pjL ready)

        {
            const int n = lane, cs = w * 16;
            VT[cs+ 0][n] = f2bf(v0.x); VT[cs+ 1][n] = f2bf(v0.y);
            VT[cs+ 2][n] = f2bf(v0.z); VT[cs+ 3][n] = f2bf(v0.w);
            VT[cs+ 4][n] = f2bf(v1.x); VT[cs+ 5][n] = f2bf(v1.y);
            VT[cs+ 6][n] = f2bf(v1.z); VT[cs+ 7][n] = f2bf(v1.w);
            VT[cs+ 8][n] = f2bf(v2.x); VT[cs+ 9][n] = f2bf(v2.y);
            VT[cs+10][n] = f2bf(v2.z); VT[cs+11][n] = f2bf(v2.w);
            VT[cs+12][n] = f2bf(v3.x); VT[cs+13][n] = f2bf(v3.y);
            VT[cs+14][n] = f2bf(v3.z); VT[cs+15][n] = f2bf(v3.w);
        }

        float s2 = k0.x*k0.x + k0.y*k0.y + k0.z*k0.z + k0.w*k0.w
                 + k1.x*k1.x + k1.y*k1.y + k1.z*k1.z + k1.w*k1.w
                 + k2.x*k2.x + k2.y*k2.y + k2.z*k2.z + k2.w*k2.w
                 + k3.x*k3.x + k3.y*k3.y + k3.z*k3.z + k3.w*k3.w;
        s2 += __shfl_xor(s2, 16);
        s2 += __shfl_xor(s2, 32);
        U8 a0, a1;
        a0.b[0]=(__bf16)k0.x; a0.b[1]=(__bf16)k0.y; a0.b[2]=(__bf16)k0.z; a0.b[3]=(__bf16)k0.w;
        a0.b[4]=(__bf16)k1.x; a0.b[5]=(__bf16)k1.y; a0.b[6]=(__bf16)k1.z; a0.b[7]=(__bf16)k1.w;
        a1.b[0]=(__bf16)k2.x; a1.b[1]=(__bf16)k2.y; a1.b[2]=(__bf16)k2.z; a1.b[3]=(__bf16)k2.w;
        a1.b[4]=(__bf16)k3.x; a1.b[5]=(__bf16)k3.y; a1.b[6]=(__bf16)k3.z; a1.b[7]=(__bf16)k3.w;

        if (tt + 1 < ntiles) {
            const float* vs = vbase + (size_t)(tt + 1) * 65536;
            v0 = *(const float4*)(vs);
            v1 = *(const float4*)(vs + 4);
            v2 = *(const float4*)(vs + 8);
            v3 = *(const float4*)(vs + 12);
            const float* ks_ = kbase + (size_t)(tt + 1) * 65536;
            k0 = *(const float4*)(ks_);
            k1 = *(const float4*)(ks_ + 4);
            k2 = *(const float4*)(ks_ + 32);
            k3 = *(const float4*)(ks_ + 36);
        }

        // ---- S = K @ proj^T : ks=0 all-register, ks=1 from pjL ----
        f32x4 sacc[16];
#pragma unroll
        for (int i = 0; i < 16; ++i) sacc[i] = (f32x4){0.f, 0.f, 0.f, 0.f};
#pragma unroll
        for (int ni = 0; ni < 16; ++ni)
            sacc[ni] = mfma16(a0.v, pb0r[ni], sacc[ni]);
#pragma unroll
        for (int ni = 0; ni < 16; ++ni) {
            bf16x8 pb1 = *(const bf16x8*)&pjL[(16*ni + l15)*64 + ((32 + 8*hh) ^ ((l15 & 7) << 3))];
            sacc[ni] = mfma16(a1.v, pb1, sacc[ni]);
        }

        float pm[4];
#pragma unroll
        for (int r = 0; r < 4; ++r) {
            float m01 = fmaxf(sacc[0][r], sacc[1][r]);
#pragma unroll
            for (int ni = 2; ni < 16; ++ni) m01 = fmaxf(m01, sacc[ni][r]);
            pm[r] = m01;
        }
#pragma unroll
        for (int msk = 1; msk <= 8; msk <<= 1)
#pragma unroll
            for (int r = 0; r < 4; ++r)
                pm[r] = fmaxf(pm[r], __shfl_xor(pm[r], msk));
        float offv[4];
#pragma unroll
        for (int r = 0; r < 4; ++r) {
            float s2r = __shfl(s2, (lane & 48) + 4*hh + r);
            offv[r] = pm[r] + DN_SCALE * s2r;
        }

#pragma unroll
        for (int ni = 0; ni < 16; ++ni) {
            float e0 = __expf(sacc[ni][0] - offv[0]);
            float e1 = __expf(sacc[ni][1] - offv[1]);
            float e2 = __expf(sacc[ni][2] - offv[2]);
            float e3 = __expf(sacc[ni][3] - offv[3]);
            ksacc[ni] += e0 + e1 + e2 + e3;
            P4 pk;
            pk.b[0]=(__bf16)e0; pk.b[1]=(__bf16)e1; pk.b[2]=(__bf16)e2; pk.b[3]=(__bf16)e3;
            const int colp = (16*w + 4*hh) ^ (8*(ni & 7));
            *(uint2*)&kpT[16*ni + l15][colp] = pk.u2;
        }
        __syncthreads();   // B: kpT + VT ready (t+1 loads long since landed)

#pragma unroll
        for (int ks = 0; ks < 2; ++ks) {
            bf16x8 am[4], bv[4];
#pragma unroll
            for (int mi = 0; mi < 4; ++mi) {
                const int row = 64*w + 16*mi + l15;
                const int s = (4*w + mi) & 7;
                am[mi] = *(const bf16x8*)&kpT[row][8*((4*ks + hh) ^ s)];
            }
#pragma unroll
            for (int ni = 0; ni < 4; ++ni)
                bv[ni] = *(const bf16x8*)&VT[16*ni + l15][ks*32 + 8*hh];
#pragma unroll
            for (int mi = 0; mi < 4; ++mi)
#pragma unroll
                for (int ni = 0; ni < 4; ++ni)
                    cacc[mi][ni] = mfma16(am[mi], bv[ni], cacc[mi][ni]);
        }
    }

#pragma unroll
    for (int ni = 0; ni < 16; ++ni) {
        ksacc[ni] += __shfl_xor(ksacc[ni], 16);
        ksacc[ni] += __shfl_xor(ksacc[ni], 32);
    }
    __syncthreads();
    float* ksW = (float*)&VT[0][0];
    if (hh == 0) {
#pragma unroll
        for (int ni = 0; ni < 16; ++ni)
            ksW[w*256 + 16*ni + l15] = ksacc[ni];
    }
    __syncthreads();
    const int pc = blockIdx.x;
    if (tid < 256)
        ksum_part[(size_t)pc * 256 + tid] = ksW[tid] + ksW[256 + tid]
                                          + ksW[512 + tid] + ksW[768 + tid];
    float* cp = ctx_part + (size_t)pc * 256 * 64;
#pragma unroll
    for (int mi = 0; mi < 4; ++mi)
#pragma unroll
        for (int ni = 0; ni < 4; ++ni)
#pragma unroll
            for (int r = 0; r < 4; ++r)
                cp[(64*w + 16*mi + 4*hh + r) * 64 + 16*ni + l15] = cacc[mi][ni][r];
}

// ------------------------------------------------------------ reduce ------
// R15: grid = 64 bh * 8 parts (512 blocks, 2/CU) — doubles latency-hiding
// contexts for the 33MB partial gather. Writes ctxT SWIZZLED:
// col = m ^ ((dh&7)<<3).
__global__ __launch_bounds__(256) void k_reduce(const float* __restrict__ ctx_part,
                                                const float* __restrict__ ksum_part,
                                                unsigned short* __restrict__ ctxT,
                                                float* __restrict__ ksum, int nchunk) {
    const int bh = blockIdx.x >> 3, part = blockIdx.x & 7;
    const int t = threadIdx.x;
    const int m = part*32 + (t & 31);
    const int dq = t >> 5;                        // 8 groups of 8 dh
    const float* cp = ctx_part + (size_t)bh * nchunk * 16384 + m*64 + dq*8;
    f32x4 s[2];
#pragma unroll
    for (int j = 0; j < 2; ++j) s[j] = *(const f32x4*)(cp + j*4);
    for (int c = 1; c < nchunk; ++c) {
        const float* cc = cp + (size_t)c * 16384;
#pragma unroll
        for (int j = 0; j < 2; ++j) {
            f32x4 a = *(const f32x4*)(cc + j*4);
            s[j] += a;
        }
    }
    unsigned short* ct = ctxT + (size_t)bh * 16384;
#pragma unroll
    for (int j = 0; j < 2; ++j)
#pragma unroll
        for (int e = 0; e < 4; ++e) {
            const int dh = dq*8 + j*4 + e;
            ct[dh * 256 + (m ^ ((dh & 7) << 3))] = f2bf(s[j][e]);
        }
    if (t < 32) {
        const int m2 = part*32 + t;
        const float* kp_ = ksum_part + (size_t)bh * nchunk * 256;
        float ks = 0.f;
        for (int c = 0; c < nchunk; ++c) ks += kp_[c*256 + m2];
        ksum[(size_t)bh * 256 + m2] = ks;
    }
}

// ------------------------------------------------------------- k_qout -----
// R15: tile-end sched_barrier REMOVED — lets the compiler pipeline tile
// t+1's Q-convert/S-GEMM under tile t's den-shfl chain + epilogue stores.
// (uL is wave-private; same-wave DS ops execute in issue order -> safe.)
// Inner rule-#18 fences (uL write->read) kept.
__global__ __launch_bounds__(256) void k_qout(const float* __restrict__ qg,
                                              const unsigned short* __restrict__ projs_swz,
                                              const unsigned short* __restrict__ ctxT,
                                              const float* __restrict__ ksum,
                                              unsigned short* __restrict__ attn) {
    const int lb = (blockIdx.x & 7) * 128 + (blockIdx.x >> 3);   // XCD swizzle
    const int bh = lb >> 4, rg = lb & 15;
    const int b = bh >> 4, h = bh & 15;
    const int tid = threadIdx.x;
    const int w = tid >> 6, lane = tid & 63, l15 = lane & 15, hh = lane >> 4;

    __shared__ __align__(16) unsigned short pjL[256 * 64];   // 32 KB
    __shared__ __align__(16) unsigned short ctxL[64 * 256];  // 32 KB
    __shared__ __align__(16) unsigned short uL[4][16 * 128]; // 16 KB

#pragma unroll
    for (int i = 0; i < 8; ++i) {
        const int blk = i*4 + w;
        gload16((const char*)projs_swz + blk*1024 + lane*16, (char*)pjL + blk*1024);
        gload16((const char*)(ctxT + (size_t)bh * 16384) + blk*1024 + lane*16,
                (char*)ctxL + blk*1024);
    }

    float ksr[16];
#pragma unroll
    for (int ni = 0; ni < 16; ++ni)
        ksr[ni] = ksum[(size_t)bh * 256 + 16*ni + l15];

    const float* qtile = qg + (size_t)(b*4096 + rg*256 + 16*w + l15) * 1024 + h*64 + hh*8;

    float4 qA[4], qB[4];
    qA[0] = *(const float4*)(qtile);
    qA[1] = *(const float4*)(qtile + 4);
    qA[2] = *(const float4*)(qtile + 32);
    qA[3] = *(const float4*)(qtile + 36);

    __syncthreads();   // pjL + ctxL ready (drains gload16)

#pragma unroll
    for (int t = 0; t < 4; ++t) {
        const float4* qc = (t & 1) ? qB : qA;
        float4*       qn = (t & 1) ? qA : qB;

        U8 a0, a1;
        a0.b[0]=(__bf16)qc[0].x; a0.b[1]=(__bf16)qc[0].y; a0.b[2]=(__bf16)qc[0].z; a0.b[3]=(__bf16)qc[0].w;
        a0.b[4]=(__bf16)qc[1].x; a0.b[5]=(__bf16)qc[1].y; a0.b[6]=(__bf16)qc[1].z; a0.b[7]=(__bf16)qc[1].w;
        a1.b[0]=(__bf16)qc[2].x; a1.b[1]=(__bf16)qc[2].y; a1.b[2]=(__bf16)qc[2].z; a1.b[3]=(__bf16)qc[2].w;
        a1.b[4]=(__bf16)qc[3].x; a1.b[5]=(__bf16)qc[3].y; a1.b[6]=(__bf16)qc[3].z; a1.b[7]=(__bf16)qc[3].w;

        if (t < 3) {
            const float* qs = qtile + (size_t)(t + 1) * 65536;
            qn[0] = *(const float4*)(qs);
            qn[1] = *(const float4*)(qs + 4);
            qn[2] = *(const float4*)(qs + 32);
            qn[3] = *(const float4*)(qs + 36);
        }

        // ---- S_q GEMM: B-frags from swizzled pjL ----
        f32x4 sacc[16];
#pragma unroll
        for (int i = 0; i < 16; ++i) sacc[i] = (f32x4){0.f, 0.f, 0.f, 0.f};
#pragma unroll
        for (int ni = 0; ni < 16; ++ni) {
            bf16x8 pb0 = *(const bf16x8*)&pjL[(16*ni + l15)*64 + ((8*hh) ^ ((l15 & 7) << 3))];
            sacc[ni] = mfma16(a0.v, pb0, sacc[ni]);
        }
#pragma unroll
        for (int ni = 0; ni < 16; ++ni) {
            bf16x8 pb1 = *(const bf16x8*)&pjL[(16*ni + l15)*64 + ((32 + 8*hh) ^ ((l15 & 7) << 3))];
            sacc[ni] = mfma16(a1.v, pb1, sacc[ni]);
        }

        float dp[4] = {0.f, 0.f, 0.f, 0.f};
        f32x4 nacc[4];
#pragma unroll
        for (int i = 0; i < 4; ++i) nacc[i] = (f32x4){0.f, 0.f, 0.f, 0.f};

        // ---- phase A: u=exp for ni 0-7 -> uL half; GEMM ks 0-3 ----
#pragma unroll
        for (int ni = 0; ni < 8; ++ni) {
#pragma unroll
            for (int r = 0; r < 4; ++r) {
                float e = __expf(sacc[ni][r]);
                dp[r] += e * ksr[ni];
                const int row = 4*hh + r;
                uL[w][row*128 + ((16*ni + l15) ^ ((row & 7) << 3))] = f2bf(e);
            }
        }
        asm volatile("s_waitcnt lgkmcnt(0)" ::: "memory");
        __builtin_amdgcn_sched_barrier(0);
#pragma unroll
        for (int ks = 0; ks < 4; ++ks) {
            bf16x8 a = *(const bf16x8*)&uL[w][l15*128 + ((ks*32 + 8*hh) ^ ((l15 & 7) << 3))];
#pragma unroll
            for (int ni = 0; ni < 4; ++ni) {
                bf16x8 bb = *(const bf16x8*)&ctxL[(16*ni + l15)*256
                                                  + ((ks*32 + 8*hh) ^ ((l15 & 7) << 3))];
                nacc[ni] = mfma16(a, bb, nacc[ni]);
            }
        }
        asm volatile("s_waitcnt lgkmcnt(0)" ::: "memory");
        __builtin_amdgcn_sched_barrier(0);

        // ---- phase B: u=exp for ni 8-15 -> uL half; GEMM ks 4-7 ----
#pragma unroll
        for (int ni = 8; ni < 16; ++ni) {
#pragma unroll
            for (int r = 0; r < 4; ++r) {
                float e = __expf(sacc[ni][r]);
                dp[r] += e * ksr[ni];
                const int row = 4*hh + r;
                uL[w][row*128 + ((16*(ni-8) + l15) ^ ((row & 7) << 3))] = f2bf(e);
            }
        }
        asm volatile("s_waitcnt lgkmcnt(0)" ::: "memory");
        __builtin_amdgcn_sched_barrier(0);
#pragma unroll
        for (int ks = 4; ks < 8; ++ks) {
            bf16x8 a = *(const bf16x8*)&uL[w][l15*128 + (((ks-4)*32 + 8*hh) ^ ((l15 & 7) << 3))];
#pragma unroll
            for (int ni = 0; ni < 4; ++ni) {
                bf16x8 bb = *(const bf16x8*)&ctxL[(16*ni + l15)*256
                                                  + ((ks*32 + 8*hh) ^ ((l15 & 7) << 3))];
                nacc[ni] = mfma16(a, bb, nacc[ni]);
            }
        }

        // ---- den reduce (in-wave) + epilogue ----
#pragma unroll
        for (int msk = 1; msk <= 8; msk <<= 1)
#pragma unroll
            for (int r = 0; r < 4; ++r)
                dp[r] += __shfl_xor(dp[r], msk);

#pragma unroll
        for (int r = 0; r < 4; ++r) {
            const float rd = 1.f / dp[r];
            const int grow = rg*256 + t*64 + 16*w + 4*hh + r;
            unsigned short* dst = attn + (size_t)(b*4096 + grow) * 1024 + h*64;
#pragma unroll
            for (int ni = 0; ni < 4; ++ni)
                dst[16*ni + l15] = f2bf(nacc[ni][r] * rd);
        }
        // (tile-end sched_barrier removed — allow cross-tile pipelining)
    }
}

// ------------------------------------------------------------ k_linear ----
// m97 structure + XCD swizzle (R14).
__global__ __launch_bounds__(256) void k_linear(const unsigned short* __restrict__ A,
                                                const unsigned short* __restrict__ Wb,
                                                const float* __restrict__ bias,
                                                float* __restrict__ out) {
    const int lb = (blockIdx.x & 7) * 128 + (blockIdx.x >> 3);   // XCD swizzle
    const int bm = lb >> 3, bn = lb & 7;
    const int tid = threadIdx.x;
    const int w = tid >> 6, lane = tid & 63, l15 = lane & 15, hh = lane >> 4;
    const int wm = w >> 1, wn = w & 1;
    const int m0 = bm * 128, n0 = bn * 128;

    __shared__ __align__(16) unsigned short As[128 * 64];
    __shared__ __align__(16) unsigned short Bs[128 * 64];

    const int srow = lane >> 3;
    const int scol = (lane & 7) * 8;

    f32x4 acc[4][4];
#pragma unroll
    for (int i = 0; i < 4; ++i)
#pragma unroll
        for (int j = 0; j < 4; ++j) acc[i][j] = (f32x4){0.f, 0.f, 0.f, 0.f};

    for (int kt = 0; kt < 16; ++kt) {
        __syncthreads();
#pragma unroll
        for (int i = 0; i < 4; ++i) {
            const int rr = (w*4 + i)*8 + srow;
            gload16(A  + (size_t)(m0 + rr) * 1024 + kt*64 + scol, &As[(w*4 + i) * 512]);
            gload16(Wb + (size_t)(n0 + rr) * 1024 + kt*64 + scol, &Bs[(w*4 + i) * 512]);
        }
        __syncthreads();
#pragma unroll
        for (int ks = 0; ks < 2; ++ks) {
            bf16x8 af[4], bw[4];
#pragma unroll
            for (int mi = 0; mi < 4; ++mi)
                af[mi] = *(const bf16x8*)&As[(wm*64 + 16*mi + l15) * 64 + ks*32 + 8*hh];
#pragma unroll
            for (int ni = 0; ni < 4; ++ni)
                bw[ni] = *(const bf16x8*)&Bs[(wn*64 + 16*ni + l15) * 64 + ks*32 + 8*hh];
#pragma unroll
            for (int mi = 0; mi < 4; ++mi)
#pragma unroll
                for (int ni = 0; ni < 4; ++ni)
                    acc[mi][ni] = mfma16(af[mi], bw[ni], acc[mi][ni]);
        }
    }

    float bs[4];
#pragma unroll
    for (int ni = 0; ni < 4; ++ni) bs[ni] = bias[n0 + wn*64 + 16*ni + l15];
#pragma unroll
    for (int mi = 0; mi < 4; ++mi) {
        const int row = m0 + wm*64 + 16*mi + 4*hh;
#pragma unroll
        for (int r = 0; r < 4; ++r) {
            float* o = out + (size_t)(row + r) * 1024 + n0 + wn*64;
#pragma unroll
            for (int ni = 0; ni < 4; ++ni)
                o[16*ni + l15] = acc[mi][ni][r] + bs[ni];
        }
    }
}

// ------------------------------------------------------------ launch ------
extern "C" void kernel_launch(void* const* d_in, const int* in_sizes, int n_in,
                              void* d_out, int out_size, void* d_ws, size_t ws_size,
                              hipStream_t stream) {
    const float* q    = (const float*)d_in[0];
    const float* k    = (const float*)d_in[1];
    const float* v    = (const float*)d_in[2];
    const float* W    = (const float*)d_in[3];
    const float* bias = (const float*)d_in[4];
    const float* proj = (const float*)d_in[5];
    float* out = (float*)d_out;

    // nchunk=8 (R9/R12-proven)
    int nchunk = 8;
    while (nchunk > 4) {
        size_t need = 33554432ull + 2097152 + 2097152 + 65536 + 32768 + 32768
                    + (size_t)nchunk * 65536
                    + (size_t)nchunk * 4194304
                    + 4096;
        if (need <= ws_size) break;
        nchunk >>= 1;
    }
    const int cshift = (nchunk == 8) ? 3 : 2;
    const int ntiles = 64 / nchunk;

    char* ws = (char*)d_ws;
    size_t off = 0;
    unsigned short* attn  = (unsigned short*)(ws + off); off += 33554432;
    unsigned short* ctxT  = (unsigned short*)(ws + off); off += 2097152;
    unsigned short* Wb    = (unsigned short*)(ws + off); off += 2097152;
    float*          ksum  = (float*)(ws + off);          off += 65536;
    unsigned short* projs = (unsigned short*)(ws + off); off += 32768;
    unsigned short* projz = (unsigned short*)(ws + off); off += 32768;
    float*          ksump = (float*)(ws + off);          off += (size_t)nchunk * 65536;
    float*          ctxp  = (float*)(ws + off);          off += (size_t)nchunk * 4194304;

    k_prep<<<dim3(4096), dim3(256), 0, stream>>>(W, proj, Wb, projs, projz);
    k_ctx<<<dim3(64 * nchunk), dim3(256), 0, stream>>>(k, v, projs, projz, ctxp, ksump,
                                                       cshift, ntiles);
    k_reduce<<<dim3(512), dim3(256), 0, stream>>>(ctxp, ksump, ctxT, ksum, nchunk);
    k_qout<<<dim3(1024), dim3(256), 0, stream>>>(q, projz, ctxT, ksum, attn);
    k_linear<<<dim3(1024), dim3(256), 0, stream>>>(attn, Wb, bias, out);
}